// Round 1
// baseline (274.468 us; speedup 1.0000x reference)
//
#include <hip/hip_runtime.h>
#include <math.h>

// Problem constants (DivEncoder): x[N,H] -> per-group (D groups, V=16) conv to U=64,
// ELU, conv U->1, row-wise L2 normalize. All fp32.
#define D_ 512
#define H_ 8192
#define U_ 64
#define V_ 16
#define N_ 4096

// Kernel 1: compute unnormalized y[n,d] into d_out.
// Grid: (N/64) * (D/4) = 64 * 128 = 8192 blocks, 256 threads = 4 waves.
// Wave w of a block handles group d = d_tile*4 + w (wave-uniform -> scalar
// loads for W1/b1/W2); lane l handles row n = n_tile*64 + l.
// Per-lane x load = 64 B (4x float4); the 4 waves of a block cover 4
// consecutive d for the same 64 rows, so each 128-B line of x is fully
// consumed within the block.
__global__ __launch_bounds__(256) void k1_div_encoder(
        const float* __restrict__ x,
        const float* __restrict__ W1,
        const float* __restrict__ b1,
        const float* __restrict__ W2,
        const float* __restrict__ b2,
        float* __restrict__ y) {
    const int tid  = threadIdx.x;
    const int lane = tid & 63;
    // readfirstlane forces the wave id into an SGPR so the compiler can prove
    // all W1/b1/W2 addressing uniform -> s_load + v_fmac(v,s,v).
    const int wave = __builtin_amdgcn_readfirstlane(tid >> 6);

    const int n_tile = blockIdx.x & 63;   // fast index: 64 n-tiles
    const int d_tile = blockIdx.x >> 6;   // 128 d-tiles
    const int n = n_tile * 64 + lane;
    const int d = d_tile * 4 + wave;

    // Load this thread's 16 x values (64 B, 16B-aligned).
    const float4* xp = (const float4*)(x + (size_t)n * H_ + (size_t)d * V_);
    float4 xr0 = xp[0];
    float4 xr1 = xp[1];
    float4 xr2 = xp[2];
    float4 xr3 = xp[3];
    float xv[16];
    xv[0]=xr0.x; xv[1]=xr0.y; xv[2]=xr0.z; xv[3]=xr0.w;
    xv[4]=xr1.x; xv[5]=xr1.y; xv[6]=xr1.z; xv[7]=xr1.w;
    xv[8]=xr2.x; xv[9]=xr2.y; xv[10]=xr2.z; xv[11]=xr2.w;
    xv[12]=xr3.x; xv[13]=xr3.y; xv[14]=xr3.z; xv[15]=xr3.w;

    const float* __restrict__ w1  = W1 + (size_t)d * (U_ * V_);
    const float* __restrict__ bb1 = b1 + (size_t)d * U_;
    const float* __restrict__ w2  = W2 + (size_t)d * U_;

    float acc = 0.0f;
    #pragma unroll 4
    for (int u = 0; u < U_; ++u) {
        const float* __restrict__ w = w1 + u * V_;
        float h = bb1[u];
        #pragma unroll
        for (int v = 0; v < V_; ++v) {
            h = fmaf(w[v], xv[v], h);
        }
        // ELU: jax.nn.elu = x>0 ? x : expm1(x). __expf(h)-1 is accurate enough
        // (abs err ~1e-7) vs the 5.3e-3 threshold.
        float e = (h > 0.0f) ? h : (__expf(h) - 1.0f);
        acc = fmaf(w2[u], e, acc);
    }

    y[(size_t)n * D_ + d] = acc + b2[d];
}

// Kernel 2: row-wise L2 normalize in place. One block (256 threads) per row;
// each thread owns 2 of the 512 row elements. Coalesced 1 KB accesses.
__global__ __launch_bounds__(256) void k2_l2_normalize(float* __restrict__ y) {
    const int n = blockIdx.x;
    const int t = threadIdx.x;
    float* row = y + (size_t)n * D_;

    float v0 = row[t];
    float v1 = row[t + 256];
    float ss = v0 * v0 + v1 * v1;

    // Wave reduction (64 lanes).
    #pragma unroll
    for (int off = 32; off > 0; off >>= 1) {
        ss += __shfl_down(ss, off, 64);
    }

    __shared__ float wsum[4];
    if ((t & 63) == 0) wsum[t >> 6] = ss;
    __syncthreads();
    const float tot = wsum[0] + wsum[1] + wsum[2] + wsum[3];

    // torch F.normalize semantics: y / max(||y||, eps), eps = 1e-12
    const float scale = 1.0f / fmaxf(sqrtf(tot), 1e-12f);

    row[t]       = v0 * scale;
    row[t + 256] = v1 * scale;
}

extern "C" void kernel_launch(void* const* d_in, const int* in_sizes, int n_in,
                              void* d_out, int out_size, void* d_ws, size_t ws_size,
                              hipStream_t stream) {
    const float* x  = (const float*)d_in[0];
    const float* W1 = (const float*)d_in[1];
    const float* b1 = (const float*)d_in[2];
    const float* W2 = (const float*)d_in[3];
    const float* b2 = (const float*)d_in[4];
    float* y = (float*)d_out;  // [N, D] fp32

    // Kernel 1: unnormalized y -> d_out
    k1_div_encoder<<<dim3((N_ / 64) * (D_ / 4)), dim3(256), 0, stream>>>(
        x, W1, b1, W2, b2, y);
    // Kernel 2: in-place row L2 normalize
    k2_l2_normalize<<<dim3(N_), dim3(256), 0, stream>>>(y);
}

// Round 2
// 239.206 us; speedup vs baseline: 1.1474x; 1.1474x over previous
//
#include <hip/hip_runtime.h>
#include <math.h>

// DivEncoder: x[N,H] -> per-group (D=512 groups, V=16) conv to U=64, ELU,
// conv U->1, row-wise L2 normalize. All fp32 in/out.
#define D_ 512
#define H_ 8192
#define U_ 64
#define V_ 16
#define N_ 4096

#define ROWS_PER_WAVE 256                 // rows each wave processes for its group
#define NB_N (N_ / ROWS_PER_WAVE)         // 16 row-blocks
#define TILES (ROWS_PER_WAVE / 16)        // 16 MFMA row-tiles per wave

typedef __bf16 bf16x8 __attribute__((ext_vector_type(8)));
typedef float f32x4 __attribute__((ext_vector_type(4)));

// Kernel 1: unnormalized y[n,d] via split-precision bf16 MFMA.
//
// Per wave: one group d (block of 4 waves = 4 consecutive d), 256 rows.
// conv1 as per-group GEMM via mfma_f32_16x16x32_bf16, A = W1 chunk (16u x 32k),
// B = x^T (32k x 16 rows). Split trick: K=32 holds [hi | lo]:
//   A = [w_hi (k=0..15) | w_lo (k=16..31)]
//   MFMA1 with B = [x_hi | x_hi]  -> (w_hi + w_lo) * x_hi = w * x_hi
//   MFMA2 with B = [x_lo | x_lo]  -> w * x_lo
// Sum = w * x exact to ~2^-17 relative (fp32 accumulate inside MFMA).
//
// Fragment layouts (gfx950, HW-verified per guide):
//   A: m = lane&15, k = (lane>>4)*8 + j   (j = 0..7)
//   B: n = lane&15, k = (lane>>4)*8 + j
//   C/D: n(col) = lane&15, m(row) = (lane>>4)*4 + reg
__global__ __launch_bounds__(256) void k1_div_encoder(
        const float* __restrict__ x,
        const float* __restrict__ W1,
        const float* __restrict__ b1,
        const float* __restrict__ W2,
        const float* __restrict__ b2,
        float* __restrict__ y) {
    const int tid  = threadIdx.x;
    const int lane = tid & 63;
    const int wave = __builtin_amdgcn_readfirstlane(tid >> 6);
    const int q    = lane >> 4;   // quad 0..3
    const int m    = lane & 15;   // A: u_local; B: batch row; D: col (batch row)

    const int dblk = blockIdx.x & 127;   // fast: 128 d-tiles (W1 L2 locality)
    const int nblk = blockIdx.x >> 7;    // 16 row-blocks
    const int d  = dblk * 4 + wave;
    const int r0 = nblk * ROWS_PER_WAVE;

    const int vbase = (q & 1) * 8;       // which 8 v's this quad holds

    // ---- per-group setup (amortized over 256 rows) ----
    // A-frags: quads 0,1 hold w_hi, quads 2,3 hold w_lo (same v's).
    bf16x8 Afrag[4];
    #pragma unroll
    for (int c = 0; c < 4; ++c) {
        const float* wp = W1 + ((size_t)d * U_ + c * 16 + m) * V_ + vbase;
        f32x4 w0 = *(const f32x4*)wp;
        f32x4 w1v = *(const f32x4*)(wp + 4);
        float wf[8] = {w0.x, w0.y, w0.z, w0.w, w1v.x, w1v.y, w1v.z, w1v.w};
        bf16x8 a;
        if (q < 2) {
            #pragma unroll
            for (int i = 0; i < 8; ++i) a[i] = (__bf16)wf[i];
        } else {
            #pragma unroll
            for (int i = 0; i < 8; ++i) {
                __bf16 h = (__bf16)wf[i];
                a[i] = (__bf16)(wf[i] - (float)h);
            }
        }
        Afrag[c] = a;
    }

    // b1 / W2 frags in C/D layout: u_local = q*4 + r for chunk c.
    f32x4 b1frag[4], w2frag[4];
    #pragma unroll
    for (int c = 0; c < 4; ++c) {
        b1frag[c] = *(const f32x4*)(b1 + (size_t)d * U_ + c * 16 + q * 4);
        w2frag[c] = *(const f32x4*)(W2 + (size_t)d * U_ + c * 16 + q * 4);
    }
    const float b2s = b2[d];

    // ---- row-tile loop ----
    for (int t = 0; t < TILES; ++t) {
        const int row = r0 + t * 16 + m;
        const float* xp = x + (size_t)row * H_ + d * V_ + vbase;
        f32x4 x0 = *(const f32x4*)xp;
        f32x4 x1 = *(const f32x4*)(xp + 4);
        float xf[8] = {x0.x, x0.y, x0.z, x0.w, x1.x, x1.y, x1.z, x1.w};

        bf16x8 bhi, blo;
        #pragma unroll
        for (int i = 0; i < 8; ++i) {
            __bf16 h = (__bf16)xf[i];
            bhi[i] = h;
            blo[i] = (__bf16)(xf[i] - (float)h);
        }

        float partial = 0.0f;
        #pragma unroll
        for (int c = 0; c < 4; ++c) {
            f32x4 acc = b1frag[c];
            acc = __builtin_amdgcn_mfma_f32_16x16x32_bf16(Afrag[c], bhi, acc, 0, 0, 0);
            acc = __builtin_amdgcn_mfma_f32_16x16x32_bf16(Afrag[c], blo, acc, 0, 0, 0);
            #pragma unroll
            for (int r = 0; r < 4; ++r) {
                float h = acc[r];
                float e = (h > 0.0f) ? h : (__expf(h) - 1.0f);  // elu
                partial = fmaf(w2frag[c][r], e, partial);
            }
        }
        // lanes {m, m+16, m+32, m+48} hold disjoint u-subsets of row's dot
        partial += __shfl_xor(partial, 16, 64);
        partial += __shfl_xor(partial, 32, 64);
        if (q == 0) {
            y[(size_t)(r0 + t * 16 + m) * D_ + d] = partial + b2s;
        }
    }
}

// Kernel 2: row-wise L2 normalize in place. One block (256 threads) per row.
__global__ __launch_bounds__(256) void k2_l2_normalize(float* __restrict__ y) {
    const int n = blockIdx.x;
    const int t = threadIdx.x;
    float* row = y + (size_t)n * D_;

    float v0 = row[t];
    float v1 = row[t + 256];
    float ss = v0 * v0 + v1 * v1;

    #pragma unroll
    for (int off = 32; off > 0; off >>= 1) {
        ss += __shfl_down(ss, off, 64);
    }

    __shared__ float wsum[4];
    if ((t & 63) == 0) wsum[t >> 6] = ss;
    __syncthreads();
    const float tot = wsum[0] + wsum[1] + wsum[2] + wsum[3];

    const float scale = 1.0f / fmaxf(sqrtf(tot), 1e-12f);

    row[t]       = v0 * scale;
    row[t + 256] = v1 * scale;
}

extern "C" void kernel_launch(void* const* d_in, const int* in_sizes, int n_in,
                              void* d_out, int out_size, void* d_ws, size_t ws_size,
                              hipStream_t stream) {
    const float* x  = (const float*)d_in[0];
    const float* W1 = (const float*)d_in[1];
    const float* b1 = (const float*)d_in[2];
    const float* W2 = (const float*)d_in[3];
    const float* b2 = (const float*)d_in[4];
    float* y = (float*)d_out;  // [N, D] fp32

    k1_div_encoder<<<dim3(NB_N * (D_ / 4)), dim3(256), 0, stream>>>(
        x, W1, b1, W2, b2, y);
    k2_l2_normalize<<<dim3(N_), dim3(256), 0, stream>>>(y);
}